// Round 8
// baseline (1161.444 us; speedup 1.0000x reference)
//
#include <hip/hip_runtime.h>
#include <hip/hip_bf16.h>

#define NA 100000
#define NE 800000
#define FDIM 133
#define KIN 192          // 133 padded to 3*64
#define H 256
#define NMOL 4096

typedef __attribute__((ext_vector_type(8))) short s16x8;
typedef __attribute__((ext_vector_type(4))) float f32x4;
typedef __attribute__((ext_vector_type(4))) unsigned int u32x4;

__device__ __forceinline__ float bf2f(unsigned short h) {
    unsigned u = ((unsigned)h) << 16;
    return __builtin_bit_cast(float, u);
}
__device__ __forceinline__ unsigned short f2bf(float f) {
    unsigned u = __builtin_bit_cast(unsigned, f);
    u = u + 0x7FFFu + ((u >> 16) & 1u);
    return (unsigned short)(u >> 16);
}
__device__ __forceinline__ void nt_store16(s16x8 v, void* p) {
    __builtin_nontemporal_store(__builtin_bit_cast(u32x4, v), (u32x4*)p);
}
__device__ __forceinline__ s16x8 nt_load16(const void* p) {
    return __builtin_bit_cast(s16x8, __builtin_nontemporal_load((const u32x4*)p));
}

// element offset (in shorts) of 16B group g (0..7) of row in a [*][64] bf16 tile,
// XOR-swizzled so ds_write_b128 staging and MFMA-frag ds_read_b128 are conflict-optimal
__device__ __forceinline__ int swz(int row, int g) {
    return row * 64 + ((g ^ (row & 7)) << 3);
}

// ================= fused agg+GEMM: T1[M][256] = AGG(X)[M][256] * BT^T + bias, stats =================
// AGG row r = (1+eps)*x'(r) + sum_{n in N(r)} x'(n), x' = AFF ? relu(x*sc+sh) : x.
// A-tile gathered straight into LDS (AGG never materialized). BM=128, BN=256, 8 waves.
template<bool AFF>
__global__ __launch_bounds__(512, 2) void gemmG_k(
    const unsigned short* __restrict__ X,
    const unsigned short* __restrict__ BT,
    const float* __restrict__ bias,
    const float* __restrict__ aSc, const float* __restrict__ aSh,
    const int* __restrict__ rowstart, const int* __restrict__ esrc,
    const float* __restrict__ epsArr, int layer,
    unsigned short* __restrict__ C,
    float* __restrict__ stSum, float* __restrict__ stSq, int M)
{
    __shared__ short lsAB[(128 + 256) * 64];   // A[128][64] | B[256][64]; reused as C-stage
    __shared__ float lsSc[256], lsSh[256], lsS[256], lsQ[256];
    short* lsA = lsAB;
    short* lsB = lsAB + 128 * 64;

    const int t = threadIdx.x;
    const int m0 = blockIdx.x * 128;
    if (t < 256) {
        lsS[t] = 0.f; lsQ[t] = 0.f;
        if (AFF) { lsSc[t] = aSc[t]; lsSh[t] = aSh[t]; }
    }
    if (AFF) __syncthreads();

    const int lane = t & 63, wid = t >> 6;
    const int wm = wid >> 2, wn = wid & 3;
    const int fr = lane & 15, fg = lane >> 4;
    const int srow = t >> 3, sg = t & 7;

    const int gr0 = m0 + srow, gr1 = m0 + srow + 64;
    int s0 = 0, e0 = 0, s1 = 0, e1 = 0;
    if (gr0 < M) { s0 = rowstart[gr0]; e0 = rowstart[gr0 + 1]; }
    if (gr1 < M) { s1 = rowstart[gr1]; e1 = rowstart[gr1 + 1]; }
    const float epv = 1.0f + epsArr[layer];

    f32x4 acc[4][4];
    #pragma unroll
    for (int i = 0; i < 4; i++)
        #pragma unroll
        for (int j = 0; j < 4; j++)
            acc[i][j] = f32x4{0.f, 0.f, 0.f, 0.f};

    s16x8 rb[4];
    auto loadB = [&](int kc) {
        #pragma unroll
        for (int p = 0; p < 4; ++p)
            rb[p] = *(const s16x8*)(BT + (size_t)(srow + p * 64) * 256 + kc * 64 + sg * 8);
    };

    loadB(0);
    for (int kc = 0; kc < 4; ++kc) {
        const int cb = kc * 64 + sg * 8;
        float sc8[8], sh8[8];
        if (AFF) {
            #pragma unroll
            for (int j = 0; j < 8; ++j) { sc8[j] = lsSc[cb + j]; sh8[j] = lsSh[cb + j]; }
        }
        auto gath = [&](int gr, int s, int e) -> s16x8 {
            float a[8] = {0,0,0,0,0,0,0,0};
            if (gr < M) {
                float b[8] = {0,0,0,0,0,0,0,0};
                {   // self term
                    s16x8 u = *(const s16x8*)(X + (size_t)gr * H + cb);
                    #pragma unroll
                    for (int j = 0; j < 8; ++j) {
                        float f = bf2f((unsigned short)u[j]);
                        if (AFF) f = fmaxf(f * sc8[j] + sh8[j], 0.f);
                        a[j] = f * epv;
                    }
                }
                int i = s;
                for (; i + 1 < e; i += 2) {   // dual-chain gather for MLP
                    int n0 = esrc[i], n1 = esrc[i + 1];
                    s16x8 u0 = *(const s16x8*)(X + (size_t)n0 * H + cb);
                    s16x8 u1 = *(const s16x8*)(X + (size_t)n1 * H + cb);
                    #pragma unroll
                    for (int j = 0; j < 8; ++j) {
                        float f0 = bf2f((unsigned short)u0[j]);
                        float f1 = bf2f((unsigned short)u1[j]);
                        if (AFF) {
                            f0 = fmaxf(f0 * sc8[j] + sh8[j], 0.f);
                            f1 = fmaxf(f1 * sc8[j] + sh8[j], 0.f);
                        }
                        a[j] += f0; b[j] += f1;
                    }
                }
                if (i < e) {
                    int n0 = esrc[i];
                    s16x8 u = *(const s16x8*)(X + (size_t)n0 * H + cb);
                    #pragma unroll
                    for (int j = 0; j < 8; ++j) {
                        float f = bf2f((unsigned short)u[j]);
                        if (AFF) f = fmaxf(f * sc8[j] + sh8[j], 0.f);
                        a[j] += f;
                    }
                }
                #pragma unroll
                for (int j = 0; j < 8; ++j) a[j] += b[j];
            }
            s16x8 o;
            #pragma unroll
            for (int j = 0; j < 8; ++j) o[j] = (short)f2bf(a[j]);
            return o;
        };
        s16x8 vA0 = gath(gr0, s0, e0);
        s16x8 vA1 = gath(gr1, s1, e1);
        *(s16x8*)&lsA[swz(srow, sg)] = vA0;
        *(s16x8*)&lsA[swz(srow + 64, sg)] = vA1;
        #pragma unroll
        for (int p = 0; p < 4; ++p)
            *(s16x8*)&lsB[swz(srow + p * 64, sg)] = rb[p];
        __syncthreads();
        if (kc < 3) loadB(kc + 1);
        #pragma unroll
        for (int ks = 0; ks < 2; ++ks) {
            s16x8 af[4], bg[4];
            #pragma unroll
            for (int mi = 0; mi < 4; ++mi)
                af[mi] = *(const s16x8*)&lsA[swz(wm * 64 + mi * 16 + fr, ks * 4 + fg)];
            #pragma unroll
            for (int ni = 0; ni < 4; ++ni)
                bg[ni] = *(const s16x8*)&lsB[swz(wn * 64 + ni * 16 + fr, ks * 4 + fg)];
            #pragma unroll
            for (int mi = 0; mi < 4; ++mi)
                #pragma unroll
                for (int ni = 0; ni < 4; ++ni)
                    acc[mi][ni] = __builtin_amdgcn_mfma_f32_16x16x32_bf16(
                        af[mi], bg[ni], acc[mi][ni], 0, 0, 0);
        }
        __syncthreads();
    }

    // LDS-staged epilogue, nt stores (T1 is read-once downstream)
    const int CST = 264;
    #pragma unroll
    for (int hm = 0; hm < 2; ++hm) {
        __syncthreads();
        if (wm == hm) {
            #pragma unroll
            for (int ni = 0; ni < 4; ++ni) {
                int lcol = wn * 64 + ni * 16 + fr;
                float bc = bias[lcol];
                float cs = 0.f, cq = 0.f;
                #pragma unroll
                for (int mi = 0; mi < 4; ++mi) {
                    #pragma unroll
                    for (int r = 0; r < 4; ++r) {
                        int rl = mi * 16 + fg * 4 + r;
                        float v = acc[mi][ni][r] + bc;
                        if (m0 + hm * 64 + rl < M) { cs += v; cq += v * v; }
                        lsAB[rl * CST + lcol] = (short)f2bf(v);
                    }
                }
                atomicAdd(&lsS[lcol], cs);
                atomicAdd(&lsQ[lcol], cq);
            }
        }
        __syncthreads();
        #pragma unroll
        for (int p = 0; p < 4; ++p) {
            int idx = p * 512 + t;
            int rl = idx >> 5;
            int col = (idx & 31) * 8;
            int row = m0 + hm * 64 + rl;
            if (row < M)
                nt_store16(*(const s16x8*)&lsAB[rl * CST + col], C + (size_t)row * H + col);
        }
    }
    __syncthreads();
    if (t < 256) {
        atomicAdd(&stSum[t], lsS[t]);
        atomicAdd(&stSq[t], lsQ[t]);
    }
}

// ================= plain GEMM (input layer & layer-second): round-7 structure + optional nt A =================
template<bool A_F32, bool AFFINE, bool RELU_OUT, bool STATS, bool NTA>
__global__ __launch_bounds__(512, 4) void gemm_k(
    const void* __restrict__ Avoid,
    const unsigned short* __restrict__ BT,
    const float* __restrict__ bias,
    const float* __restrict__ aSc, const float* __restrict__ aSh,
    unsigned short* __restrict__ C,
    float* __restrict__ stSum, float* __restrict__ stSq,
    int M, int Kpad)
{
    __shared__ short lsAB[(128 + 256) * 64];
    __shared__ float lsSc[256], lsSh[256];
    __shared__ float lsS[256], lsQ[256];
    short* lsA = lsAB;
    short* lsB = lsAB + 128 * 64;

    const int t = threadIdx.x;
    const int m0 = blockIdx.x * 128;

    if (STATS && t < 256) { lsS[t] = 0.f; lsQ[t] = 0.f; }
    if (AFFINE && t < 256) { lsSc[t] = aSc[t]; lsSh[t] = aSh[t]; }
    if (AFFINE) __syncthreads();

    const int lane = t & 63;
    const int wid = t >> 6;
    const int wm = wid >> 2, wn = wid & 3;
    const int fr = lane & 15, fg = lane >> 4;
    const int srow = t >> 3;
    const int sg = t & 7;

    f32x4 acc[4][4];
    #pragma unroll
    for (int i = 0; i < 4; i++)
        #pragma unroll
        for (int j = 0; j < 4; j++)
            acc[i][j] = f32x4{0.f, 0.f, 0.f, 0.f};

    const int nK = Kpad >> 6;
    s16x8 ra[2], rb[4];

    auto loadRegs = [&](int kc) {
        const int k0 = kc * 64;
        #pragma unroll
        for (int p = 0; p < 2; ++p) {
            int r = srow + p * 64;
            int ga = m0 + r;
            if (A_F32) {
                const float* Af = (const float*)Avoid;
                s16x8 v;
                #pragma unroll
                for (int e = 0; e < 8; ++e) {
                    int k = k0 + sg * 8 + e;
                    float f = (ga < M && k < FDIM) ? Af[(size_t)ga * FDIM + k] : 0.f;
                    v[e] = (short)f2bf(f);
                }
                ra[p] = v;
            } else {
                const unsigned short* A = (const unsigned short*)Avoid;
                s16x8 z = {0,0,0,0,0,0,0,0};
                const void* ap = A + (size_t)ga * Kpad + k0 + sg * 8;
                ra[p] = (ga < M) ? (NTA ? nt_load16(ap) : *(const s16x8*)ap) : z;
            }
        }
        #pragma unroll
        for (int p = 0; p < 4; ++p)
            rb[p] = *(const s16x8*)(BT + (size_t)(srow + p * 64) * Kpad + k0 + sg * 8);
    };
    auto writeLds = [&](int kc) {
        const int k0 = kc * 64;
        #pragma unroll
        for (int p = 0; p < 2; ++p) {
            s16x8 va = ra[p];
            if (AFFINE) {
                #pragma unroll
                for (int e = 0; e < 8; ++e) {
                    int k = k0 + sg * 8 + e;
                    float f = bf2f((unsigned short)va[e]);
                    f = fmaxf(f * lsSc[k] + lsSh[k], 0.f);
                    va[e] = (short)f2bf(f);
                }
            }
            *(s16x8*)&lsA[swz(srow + p * 64, sg)] = va;
        }
        #pragma unroll
        for (int p = 0; p < 4; ++p)
            *(s16x8*)&lsB[swz(srow + p * 64, sg)] = rb[p];
    };

    loadRegs(0);
    for (int kc = 0; kc < nK; ++kc) {
        writeLds(kc);
        __syncthreads();
        if (kc + 1 < nK) loadRegs(kc + 1);
        #pragma unroll
        for (int ks = 0; ks < 2; ++ks) {
            s16x8 af[4], bg[4];
            #pragma unroll
            for (int mi = 0; mi < 4; ++mi)
                af[mi] = *(const s16x8*)&lsA[swz(wm * 64 + mi * 16 + fr, ks * 4 + fg)];
            #pragma unroll
            for (int ni = 0; ni < 4; ++ni)
                bg[ni] = *(const s16x8*)&lsB[swz(wn * 64 + ni * 16 + fr, ks * 4 + fg)];
            #pragma unroll
            for (int mi = 0; mi < 4; ++mi)
                #pragma unroll
                for (int ni = 0; ni < 4; ++ni)
                    acc[mi][ni] = __builtin_amdgcn_mfma_f32_16x16x32_bf16(
                        af[mi], bg[ni], acc[mi][ni], 0, 0, 0);
        }
        __syncthreads();
    }

    const int CST = 264;
    #pragma unroll
    for (int hm = 0; hm < 2; ++hm) {
        __syncthreads();
        if (wm == hm) {
            #pragma unroll
            for (int ni = 0; ni < 4; ++ni) {
                int lcol = wn * 64 + ni * 16 + fr;
                float bc = bias[lcol];
                float cs = 0.f, cq = 0.f;
                #pragma unroll
                for (int mi = 0; mi < 4; ++mi) {
                    #pragma unroll
                    for (int r = 0; r < 4; ++r) {
                        int rl = mi * 16 + fg * 4 + r;
                        float v = acc[mi][ni][r] + bc;
                        if (RELU_OUT) v = fmaxf(v, 0.f);
                        if (STATS && (m0 + hm * 64 + rl < M)) { cs += v; cq += v * v; }
                        lsAB[rl * CST + lcol] = (short)f2bf(v);
                    }
                }
                if (STATS) {
                    atomicAdd(&lsS[lcol], cs);
                    atomicAdd(&lsQ[lcol], cq);
                }
            }
        }
        __syncthreads();
        #pragma unroll
        for (int p = 0; p < 4; ++p) {
            int idx = p * 512 + t;
            int rl = idx >> 5;
            int col = (idx & 31) * 8;
            int row = m0 + hm * 64 + rl;
            if (row < M)
                *(s16x8*)(C + (size_t)row * H + col) = *(const s16x8*)&lsAB[rl * CST + col];
        }
    }

    if (STATS) {
        __syncthreads();
        if (t < 256) {
            atomicAdd(&stSum[t], lsS[t]);
            atomicAdd(&stSq[t], lsQ[t]);
        }
    }
}

__global__ void bnfin_k(float* __restrict__ sum, float* __restrict__ sumsq,
                        const float* __restrict__ g, const float* __restrict__ be,
                        float* __restrict__ scOut, float* __restrict__ shOut) {
    int c = threadIdx.x;
    float mean = sum[c] * (1.0f / NA);
    float var = sumsq[c] * (1.0f / NA) - mean * mean;
    float sc = g[c] * rsqrtf(var + 1e-5f);
    scOut[c] = sc;
    shOut[c] = be[c] - mean * sc;
    sum[c] = 0.f; sumsq[c] = 0.f;
}

// ---------------- init ----------------
__global__ void zero_k(int* __restrict__ counts, float* __restrict__ st, int* __restrict__ rowstart) {
    int i = blockIdx.x * 256 + threadIdx.x;
    if (i < NA) counts[i] = 0;
    if (blockIdx.x == 0) {
        st[threadIdx.x] = 0.f; st[threadIdx.x + 256] = 0.f;
        if (threadIdx.x == 0) rowstart[NA] = NE;
    }
}

// ---------------- CSR build ----------------
__global__ void hist_k(const int* __restrict__ dst, int* __restrict__ counts) {
    int e = blockIdx.x * 256 + threadIdx.x;
    if (e < NE) atomicAdd(&counts[dst[e]], 1);
}
__global__ void scan1_k(const int* __restrict__ counts, int* __restrict__ excl, int* __restrict__ bsum) {
    __shared__ int sd[256];
    int i = blockIdx.x * 256 + threadIdx.x;
    int c = (i < NA) ? counts[i] : 0;
    sd[threadIdx.x] = c;
    __syncthreads();
    for (int off = 1; off < 256; off <<= 1) {
        int v = (threadIdx.x >= off) ? sd[threadIdx.x - off] : 0;
        __syncthreads();
        sd[threadIdx.x] += v;
        __syncthreads();
    }
    if (i < NA) excl[i] = sd[threadIdx.x] - c;
    if (threadIdx.x == 255) bsum[blockIdx.x] = sd[255];
}
__global__ void scan2_k(int* __restrict__ bsum, int nb) {
    __shared__ int sd[512];
    int t = threadIdx.x;
    int v = (t < nb) ? bsum[t] : 0;
    sd[t] = v;
    __syncthreads();
    for (int off = 1; off < 512; off <<= 1) {
        int u = (t >= off) ? sd[t - off] : 0;
        __syncthreads();
        sd[t] += u;
        __syncthreads();
    }
    if (t < nb) bsum[t] = sd[t] - v;
}
__global__ void scan3_k(int* __restrict__ rowstart, const int* __restrict__ bsum, int* __restrict__ cursor) {
    int i = blockIdx.x * 256 + threadIdx.x;
    if (i < NA) {
        int v = rowstart[i] + bsum[blockIdx.x];
        rowstart[i] = v;
        cursor[i] = v;
    }
}
__global__ void fill_k(const int* __restrict__ src, const int* __restrict__ dstArr,
                       int* __restrict__ cursor, int* __restrict__ esrc) {
    int e = blockIdx.x * 256 + threadIdx.x;
    if (e < NE) {
        int d = dstArr[e];
        int pos = atomicAdd(&cursor[d], 1);
        esrc[pos] = src[e];
    }
}

// ---------------- weight prep ----------------
__global__ void prep_all_k(const float* __restrict__ Win, const float* __restrict__ w1,
                           const float* __restrict__ w2, unsigned short* __restrict__ BTall) {
    int i = blockIdx.x * 256 + threadIdx.x;
    const int NIN = 256 * KIN;
    if (i < NIN) {
        int n = i / KIN, k = i % KIN;
        BTall[i] = (k < FDIM) ? f2bf(Win[(size_t)k * 256 + n]) : (unsigned short)0;
    } else if (i < NIN + 6 * 65536) {
        int j = i - NIN;
        int d = j >> 16, r = j & 65535;
        int n = r >> 8, k = r & 255;
        const float* W = (d & 1) ? w2 : w1;
        BTall[i] = f2bf(W[(size_t)(d >> 1) * 65536 + (size_t)k * 256 + n]);
    }
}

// ---------------- segment mean ----------------
__global__ void molstart_k(const int* __restrict__ seg, int* __restrict__ ms) {
    int m = blockIdx.x * 256 + threadIdx.x;
    if (m <= NMOL) {
        int lo = 0, hi = NA;
        while (lo < hi) { int mid = (lo + hi) >> 1; if (seg[mid] < m) lo = mid + 1; else hi = mid; }
        ms[m] = lo;
    }
}
__global__ __launch_bounds__(64) void mean_k(const unsigned short* __restrict__ X,
    const float* __restrict__ sc, const float* __restrict__ sh,
    const int* __restrict__ ms, float* __restrict__ out)
{
    int m = blockIdx.x, lane = threadIdx.x;
    int half = lane >> 5;
    int c0 = (lane & 31) * 8;
    float s8[8], h8[8];
    {
        f32x4 a = *(const f32x4*)(sc + c0), b = *(const f32x4*)(sc + c0 + 4);
        f32x4 c = *(const f32x4*)(sh + c0), d = *(const f32x4*)(sh + c0 + 4);
        #pragma unroll
        for (int e = 0; e < 4; e++) { s8[e] = a[e]; s8[e + 4] = b[e]; h8[e] = c[e]; h8[e + 4] = d[e]; }
    }
    int a = ms[m], b = ms[m + 1];
    float acc[8] = {0,0,0,0,0,0,0,0};
    for (int r = a + half; r < b; r += 2) {
        s16x8 u = *(const s16x8*)(X + (size_t)r * H + c0);
        #pragma unroll
        for (int e = 0; e < 8; e++)
            acc[e] += fmaxf(bf2f((unsigned short)u[e]) * s8[e] + h8[e], 0.f);
    }
    float inv = (b > a) ? 1.0f / (float)(b - a) : 0.0f;
    f32x4 o0, o1;
    #pragma unroll
    for (int e = 0; e < 8; e++) {
        float tot = acc[e] + __shfl_xor(acc[e], 32);
        tot *= inv;
        if (e < 4) o0[e] = tot; else o1[e - 4] = tot;
    }
    if (half == 0) {
        *(f32x4*)(out + (size_t)m * H + c0) = o0;
        *(f32x4*)(out + (size_t)m * H + c0 + 4) = o1;
    }
}

extern "C" void kernel_launch(void* const* d_in, const int* in_sizes, int n_in,
                              void* d_out, int out_size, void* d_ws, size_t ws_size,
                              hipStream_t stream) {
    const float* f_atoms = (const float*)d_in[0];
    const float* W_in_w  = (const float*)d_in[1];
    const float* W_in_b  = (const float*)d_in[2];
    const float* w1  = (const float*)d_in[3];
    const float* b1  = (const float*)d_in[4];
    const float* g1  = (const float*)d_in[5];
    const float* be1 = (const float*)d_in[6];
    const float* w2  = (const float*)d_in[7];
    const float* b2  = (const float*)d_in[8];
    const float* g2  = (const float*)d_in[9];
    const float* be2 = (const float*)d_in[10];
    const float* epsArr = (const float*)d_in[11];
    const int* edge = (const int*)d_in[12];
    const int* seg  = (const int*)d_in[13];
    float* out = (float*)d_out;

    char* w = (char*)d_ws;
    size_t off = 0;
    auto alloc = [&](size_t bytes) {
        char* p = w + off;
        off = (off + bytes + 255) & ~(size_t)255;
        return p;
    };
    unsigned short* X   = (unsigned short*)alloc((size_t)NA * H * 2);
    unsigned short* T1  = (unsigned short*)alloc((size_t)NA * H * 2);
    unsigned short* BTall = (unsigned short*)alloc(((size_t)256 * KIN + 6 * 65536) * 2);
    float* stSum = (float*)alloc(256 * 4);
    float* stSq  = (float*)alloc(256 * 4);   // contiguous with stSum
    float* sc1 = (float*)alloc(256 * 4);
    float* sh1 = (float*)alloc(256 * 4);
    float* sc2 = (float*)alloc(256 * 4);
    float* sh2 = (float*)alloc(256 * 4);
    int* counts   = (int*)alloc((size_t)NA * 4);
    int* rowstart = (int*)alloc((size_t)(NA + 1) * 4);
    int* cursor   = (int*)alloc((size_t)NA * 4);
    int* esrc     = (int*)alloc((size_t)NE * 4);
    int* bsum     = (int*)alloc(512 * 4);
    int* ms       = (int*)alloc((NMOL + 1) * 4);

    unsigned short* BTin = BTall;
    unsigned short* BT1[3], *BT2[3];
    for (int d = 0; d < 3; ++d) {
        BT1[d] = BTall + 256 * KIN + (size_t)(2 * d) * 65536;
        BT2[d] = BTall + 256 * KIN + (size_t)(2 * d + 1) * 65536;
    }

    const int* esrcIn = edge;        // edge_index[0] = src
    const int* edst   = edge + NE;   // edge_index[1] = dst

    zero_k<<<(NA + 255) / 256, 256, 0, stream>>>(counts, stSum, rowstart);
    prep_all_k<<<(256 * KIN + 6 * 65536 + 255) / 256, 256, 0, stream>>>(W_in_w, w1, w2, BTall);

    hist_k<<<(NE + 255) / 256, 256, 0, stream>>>(edst, counts);
    scan1_k<<<391, 256, 0, stream>>>(counts, rowstart, bsum);
    scan2_k<<<1, 512, 0, stream>>>(bsum, 391);
    scan3_k<<<391, 256, 0, stream>>>(rowstart, bsum, cursor);
    fill_k<<<(NE + 255) / 256, 256, 0, stream>>>(esrcIn, edst, cursor, esrc);
    molstart_k<<<(NMOL + 256) / 256, 256, 0, stream>>>(seg, ms);

    const int GB = (NA + 127) / 128;   // 782

    // x = relu(f_atoms @ W_in + b_in)
    gemm_k<true, false, true, false, false><<<GB, 512, 0, stream>>>(
        f_atoms, BTin, W_in_b, nullptr, nullptr, X, nullptr, nullptr, NA, KIN);

    for (int d = 0; d < 3; ++d) {
        // T1 = AGG(X) @ w1 + b1  (agg fused into staging; +stats)
        if (d == 0)
            gemmG_k<false><<<GB, 512, 0, stream>>>(X, BT1[d], b1 + d * 256,
                nullptr, nullptr, rowstart, esrc, epsArr, d, T1, stSum, stSq, NA);
        else
            gemmG_k<true><<<GB, 512, 0, stream>>>(X, BT1[d], b1 + d * 256,
                sc2, sh2, rowstart, esrc, epsArr, d, T1, stSum, stSq, NA);
        bnfin_k<<<1, 256, 0, stream>>>(stSum, stSq, g1 + d * 256, be1 + d * 256, sc1, sh1);
        // X = relu(BN(T1)) @ w2 + b2  (nt A loads; +stats)
        gemm_k<false, true, false, true, true><<<GB, 512, 0, stream>>>(
            T1, BT2[d], b2 + d * 256, sc1, sh1, X, stSum, stSq, NA, 256);
        bnfin_k<<<1, 256, 0, stream>>>(stSum, stSq, g2 + d * 256, be2 + d * 256, sc2, sh2);
    }

    mean_k<<<NMOL, 64, 0, stream>>>(X, sc2, sh2, ms, out);
}

// Round 9
// 884.187 us; speedup vs baseline: 1.3136x; 1.3136x over previous
//
#include <hip/hip_runtime.h>
#include <hip/hip_bf16.h>

#define NA 100000
#define NE 800000
#define FDIM 133
#define KIN 192          // 133 padded to 3*64
#define H 256
#define NMOL 4096

typedef __attribute__((ext_vector_type(8))) short s16x8;
typedef __attribute__((ext_vector_type(4))) float f32x4;
typedef __attribute__((ext_vector_type(4))) unsigned int u32x4;

__device__ __forceinline__ float bf2f(unsigned short h) {
    unsigned u = ((unsigned)h) << 16;
    return __builtin_bit_cast(float, u);
}
__device__ __forceinline__ unsigned short f2bf(float f) {
    unsigned u = __builtin_bit_cast(unsigned, f);
    u = u + 0x7FFFu + ((u >> 16) & 1u);
    return (unsigned short)(u >> 16);
}
// non-temporal 16B ops: r8 measured nt C-stores give EXACTLY logical WRITE_SIZE
// (51.5 MB) vs 151-187 MB with normal stores (L2 dirty-line amplification).
__device__ __forceinline__ void nt_store16(s16x8 v, void* p) {
    __builtin_nontemporal_store(__builtin_bit_cast(u32x4, v), (u32x4*)p);
}
__device__ __forceinline__ s16x8 nt_load16(const void* p) {
    return __builtin_bit_cast(s16x8, __builtin_nontemporal_load((const u32x4*)p));
}

// element offset (in shorts) of 16B group g (0..7) of row in a [*][64] bf16 tile,
// XOR-swizzled so ds_write_b128 staging and MFMA-frag ds_read_b128 are conflict-optimal
__device__ __forceinline__ int swz(int row, int g) {
    return row * 64 + ((g ^ (row & 7)) << 3);
}

// ---------------- GEMM: C[M][256] = A[M][Kpad] * BT[256][Kpad]^T (+bias) ----------------
// BM=128, BN=256 (full width), 8 waves, wave tile 64x64, reg-staged single-buffer LDS.
// LDS-staged epilogue + nt C stores. NTA: nt A loads (read-once streaming input).
template<bool A_F32, bool AFFINE, bool RELU_OUT, bool STATS, bool NTA>
__global__ __launch_bounds__(512, 4) void gemm_k(
    const void* __restrict__ Avoid,
    const unsigned short* __restrict__ BT,
    const float* __restrict__ bias,
    const float* __restrict__ aSc, const float* __restrict__ aSh,
    unsigned short* __restrict__ C,
    float* __restrict__ stSum, float* __restrict__ stSq,
    int M, int Kpad)
{
    __shared__ short lsAB[(128 + 256) * 64];   // A[128][64] | B[256][64]; reused as C-stage
    __shared__ float lsSc[256], lsSh[256];
    __shared__ float lsS[256], lsQ[256];
    short* lsA = lsAB;
    short* lsB = lsAB + 128 * 64;

    const int t = threadIdx.x;
    const int m0 = blockIdx.x * 128;

    if (STATS && t < 256) { lsS[t] = 0.f; lsQ[t] = 0.f; }
    if (AFFINE && t < 256) { lsSc[t] = aSc[t]; lsSh[t] = aSh[t]; }
    if (AFFINE) __syncthreads();

    const int lane = t & 63;
    const int wid = t >> 6;
    const int wm = wid >> 2, wn = wid & 3;
    const int fr = lane & 15, fg = lane >> 4;
    const int srow = t >> 3;
    const int sg = t & 7;

    f32x4 acc[4][4];
    #pragma unroll
    for (int i = 0; i < 4; i++)
        #pragma unroll
        for (int j = 0; j < 4; j++)
            acc[i][j] = f32x4{0.f, 0.f, 0.f, 0.f};

    const int nK = Kpad >> 6;
    s16x8 ra[2], rb[4];

    auto loadRegs = [&](int kc) {
        const int k0 = kc * 64;
        #pragma unroll
        for (int p = 0; p < 2; ++p) {
            int r = srow + p * 64;
            int ga = m0 + r;
            if (A_F32) {
                const float* Af = (const float*)Avoid;
                s16x8 v;
                #pragma unroll
                for (int e = 0; e < 8; ++e) {
                    int k = k0 + sg * 8 + e;
                    float f = (ga < M && k < FDIM) ? Af[(size_t)ga * FDIM + k] : 0.f;
                    v[e] = (short)f2bf(f);
                }
                ra[p] = v;
            } else {
                const unsigned short* A = (const unsigned short*)Avoid;
                s16x8 z = {0,0,0,0,0,0,0,0};
                const void* ap = A + (size_t)ga * Kpad + k0 + sg * 8;
                ra[p] = (ga < M) ? (NTA ? nt_load16(ap) : *(const s16x8*)ap) : z;
            }
        }
        #pragma unroll
        for (int p = 0; p < 4; ++p)
            rb[p] = *(const s16x8*)(BT + (size_t)(srow + p * 64) * Kpad + k0 + sg * 8);
    };
    auto writeLds = [&](int kc) {
        const int k0 = kc * 64;
        #pragma unroll
        for (int p = 0; p < 2; ++p) {
            s16x8 va = ra[p];
            if (AFFINE) {
                #pragma unroll
                for (int e = 0; e < 8; ++e) {
                    int k = k0 + sg * 8 + e;
                    float f = bf2f((unsigned short)va[e]);
                    f = fmaxf(f * lsSc[k] + lsSh[k], 0.f);
                    va[e] = (short)f2bf(f);
                }
            }
            *(s16x8*)&lsA[swz(srow + p * 64, sg)] = va;
        }
        #pragma unroll
        for (int p = 0; p < 4; ++p)
            *(s16x8*)&lsB[swz(srow + p * 64, sg)] = rb[p];
    };

    loadRegs(0);
    for (int kc = 0; kc < nK; ++kc) {
        writeLds(kc);
        __syncthreads();
        if (kc + 1 < nK) loadRegs(kc + 1);   // next-chunk loads in flight across MFMAs
        #pragma unroll
        for (int ks = 0; ks < 2; ++ks) {
            s16x8 af[4], bg[4];
            #pragma unroll
            for (int mi = 0; mi < 4; ++mi)
                af[mi] = *(const s16x8*)&lsA[swz(wm * 64 + mi * 16 + fr, ks * 4 + fg)];
            #pragma unroll
            for (int ni = 0; ni < 4; ++ni)
                bg[ni] = *(const s16x8*)&lsB[swz(wn * 64 + ni * 16 + fr, ks * 4 + fg)];
            #pragma unroll
            for (int mi = 0; mi < 4; ++mi)
                #pragma unroll
                for (int ni = 0; ni < 4; ++ni)
                    acc[mi][ni] = __builtin_amdgcn_mfma_f32_16x16x32_bf16(
                        af[mi], bg[ni], acc[mi][ni], 0, 0, 0);
        }
        __syncthreads();
    }

    // LDS-staged epilogue -> full-line coalesced nt stores
    const int CST = 264;
    #pragma unroll
    for (int hm = 0; hm < 2; ++hm) {
        __syncthreads();
        if (wm == hm) {
            #pragma unroll
            for (int ni = 0; ni < 4; ++ni) {
                int lcol = wn * 64 + ni * 16 + fr;
                float bc = bias[lcol];
                float cs = 0.f, cq = 0.f;
                #pragma unroll
                for (int mi = 0; mi < 4; ++mi) {
                    #pragma unroll
                    for (int r = 0; r < 4; ++r) {
                        int rl = mi * 16 + fg * 4 + r;
                        float v = acc[mi][ni][r] + bc;
                        if (RELU_OUT) v = fmaxf(v, 0.f);
                        if (STATS && (m0 + hm * 64 + rl < M)) { cs += v; cq += v * v; }
                        lsAB[rl * CST + lcol] = (short)f2bf(v);
                    }
                }
                if (STATS) {
                    atomicAdd(&lsS[lcol], cs);
                    atomicAdd(&lsQ[lcol], cq);
                }
            }
        }
        __syncthreads();
        #pragma unroll
        for (int p = 0; p < 4; ++p) {
            int idx = p * 512 + t;
            int rl = idx >> 5;
            int col = (idx & 31) * 8;
            int row = m0 + hm * 64 + rl;
            if (row < M)
                nt_store16(*(const s16x8*)&lsAB[rl * CST + col], C + (size_t)row * H + col);
        }
    }

    if (STATS) {
        __syncthreads();
        if (t < 256) {
            atomicAdd(&stSum[t], lsS[t]);
            atomicAdd(&stSq[t], lsQ[t]);
        }
    }
}

__global__ void bnfin_k(float* __restrict__ sum, float* __restrict__ sumsq,
                        const float* __restrict__ g, const float* __restrict__ be,
                        float* __restrict__ scOut, float* __restrict__ shOut) {
    int c = threadIdx.x;
    float mean = sum[c] * (1.0f / NA);
    float var = sumsq[c] * (1.0f / NA) - mean * mean;
    float sc = g[c] * rsqrtf(var + 1e-5f);
    scOut[c] = sc;
    shOut[c] = be[c] - mean * sc;
    sum[c] = 0.f; sumsq[c] = 0.f;
}

// ---------------- init ----------------
__global__ void zero_k(int* __restrict__ counts, float* __restrict__ st, int* __restrict__ rowstart) {
    int i = blockIdx.x * 256 + threadIdx.x;
    if (i < NA) counts[i] = 0;
    if (blockIdx.x == 0) {
        st[threadIdx.x] = 0.f; st[threadIdx.x + 256] = 0.f;
        if (threadIdx.x == 0) rowstart[NA] = NE;
    }
}

// ---------------- CSR build ----------------
__global__ void hist_k(const int* __restrict__ dst, int* __restrict__ counts) {
    int e = blockIdx.x * 256 + threadIdx.x;
    if (e < NE) atomicAdd(&counts[dst[e]], 1);
}
__global__ void scan1_k(const int* __restrict__ counts, int* __restrict__ excl, int* __restrict__ bsum) {
    __shared__ int sd[256];
    int i = blockIdx.x * 256 + threadIdx.x;
    int c = (i < NA) ? counts[i] : 0;
    sd[threadIdx.x] = c;
    __syncthreads();
    for (int off = 1; off < 256; off <<= 1) {
        int v = (threadIdx.x >= off) ? sd[threadIdx.x - off] : 0;
        __syncthreads();
        sd[threadIdx.x] += v;
        __syncthreads();
    }
    if (i < NA) excl[i] = sd[threadIdx.x] - c;
    if (threadIdx.x == 255) bsum[blockIdx.x] = sd[255];
}
__global__ void scan2_k(int* __restrict__ bsum, int nb) {
    __shared__ int sd[512];
    int t = threadIdx.x;
    int v = (t < nb) ? bsum[t] : 0;
    sd[t] = v;
    __syncthreads();
    for (int off = 1; off < 512; off <<= 1) {
        int u = (t >= off) ? sd[t - off] : 0;
        __syncthreads();
        sd[t] += u;
        __syncthreads();
    }
    if (t < nb) bsum[t] = sd[t] - v;
}
__global__ void scan3_k(int* __restrict__ rowstart, const int* __restrict__ bsum, int* __restrict__ cursor) {
    int i = blockIdx.x * 256 + threadIdx.x;
    if (i < NA) {
        int v = rowstart[i] + bsum[blockIdx.x];
        rowstart[i] = v;
        cursor[i] = v;
    }
}
__global__ void fill_k(const int* __restrict__ src, const int* __restrict__ dstArr,
                       int* __restrict__ cursor, int* __restrict__ esrc) {
    int e = blockIdx.x * 256 + threadIdx.x;
    if (e < NE) {
        int d = dstArr[e];
        int pos = atomicAdd(&cursor[d], 1);
        esrc[pos] = src[e];
    }
}

// ---------------- neighbor aggregation (round-5 proven structure) ----------------
// one row/wave; halves walk contiguous sub-ranges, 4 gathers in flight; shfl merge; nt AGG store
template<bool AFF>
__global__ __launch_bounds__(256) void agg_k(const unsigned short* __restrict__ X,
    const float* __restrict__ sc, const float* __restrict__ sh,
    const int* __restrict__ rowstart,
    const int* __restrict__ esrc, const float* __restrict__ epsArr, int layer,
    unsigned short* __restrict__ AGG)
{
    int wid = threadIdx.x >> 6, lane = threadIdx.x & 63;
    int row = blockIdx.x * 4 + wid;
    int half = lane >> 5;
    int c0 = (lane & 31) * 8;

    float s8[8], h8[8];
    if (AFF) {
        f32x4 a = *(const f32x4*)(sc + c0), b = *(const f32x4*)(sc + c0 + 4);
        f32x4 c = *(const f32x4*)(sh + c0), d = *(const f32x4*)(sh + c0 + 4);
        #pragma unroll
        for (int e = 0; e < 4; e++) { s8[e] = a[e]; s8[e + 4] = b[e]; h8[e] = c[e]; h8[e + 4] = d[e]; }
    }

    float a0[8] = {0,0,0,0,0,0,0,0}, a1[8] = {0,0,0,0,0,0,0,0};
    auto addv = [&](s16x8 u, float* a) {
        #pragma unroll
        for (int e = 0; e < 8; e++) {
            float f = bf2f((unsigned short)u[e]);
            if (AFF) f = fmaxf(f * s8[e] + h8[e], 0.f);
            a[e] += f;
        }
    };

    int s = rowstart[row], eEnd = rowstart[row + 1];
    int cnt = eEnd - s, mid = s + (cnt >> 1);
    int i = half ? mid : s;
    int end = half ? eEnd : mid;
    for (; i + 3 < end; i += 4) {
        int e0 = esrc[i], e1 = esrc[i + 1], e2 = esrc[i + 2], e3 = esrc[i + 3];
        s16x8 u0 = *(const s16x8*)(X + (size_t)e0 * H + c0);
        s16x8 u1 = *(const s16x8*)(X + (size_t)e1 * H + c0);
        s16x8 u2 = *(const s16x8*)(X + (size_t)e2 * H + c0);
        s16x8 u3 = *(const s16x8*)(X + (size_t)e3 * H + c0);
        addv(u0, a0); addv(u1, a1); addv(u2, a0); addv(u3, a1);
    }
    for (; i < end; ++i) {
        int e0 = esrc[i];
        s16x8 u = *(const s16x8*)(X + (size_t)e0 * H + c0);
        addv(u, a0);
    }

    if (half == 0) {   // self term
        float e1 = 1.0f + epsArr[layer];
        s16x8 u = *(const s16x8*)(X + (size_t)row * H + c0);
        #pragma unroll
        for (int e = 0; e < 8; e++) {
            float f = bf2f((unsigned short)u[e]);
            if (AFF) f = fmaxf(f * s8[e] + h8[e], 0.f);
            a0[e] += f * e1;
        }
    }

    s16x8 o;
    #pragma unroll
    for (int e = 0; e < 8; e++) {
        float tot = a0[e] + a1[e];
        tot += __shfl_xor(tot, 32);
        o[e] = (short)f2bf(tot);
    }
    if (half == 0)
        nt_store16(o, AGG + (size_t)row * H + c0);
}

// ---------------- weight prep ----------------
__global__ void prep_all_k(const float* __restrict__ Win, const float* __restrict__ w1,
                           const float* __restrict__ w2, unsigned short* __restrict__ BTall) {
    int i = blockIdx.x * 256 + threadIdx.x;
    const int NIN = 256 * KIN;
    if (i < NIN) {
        int n = i / KIN, k = i % KIN;
        BTall[i] = (k < FDIM) ? f2bf(Win[(size_t)k * 256 + n]) : (unsigned short)0;
    } else if (i < NIN + 6 * 65536) {
        int j = i - NIN;
        int d = j >> 16, r = j & 65535;
        int n = r >> 8, k = r & 255;
        const float* W = (d & 1) ? w2 : w1;
        BTall[i] = f2bf(W[(size_t)(d >> 1) * 65536 + (size_t)k * 256 + n]);
    }
}

// ---------------- segment mean ----------------
__global__ void molstart_k(const int* __restrict__ seg, int* __restrict__ ms) {
    int m = blockIdx.x * 256 + threadIdx.x;
    if (m <= NMOL) {
        int lo = 0, hi = NA;
        while (lo < hi) { int mid = (lo + hi) >> 1; if (seg[mid] < m) lo = mid + 1; else hi = mid; }
        ms[m] = lo;
    }
}
__global__ __launch_bounds__(64) void mean_k(const unsigned short* __restrict__ X,
    const float* __restrict__ sc, const float* __restrict__ sh,
    const int* __restrict__ ms, float* __restrict__ out)
{
    int m = blockIdx.x, lane = threadIdx.x;
    int half = lane >> 5;
    int c0 = (lane & 31) * 8;
    float s8[8], h8[8];
    {
        f32x4 a = *(const f32x4*)(sc + c0), b = *(const f32x4*)(sc + c0 + 4);
        f32x4 c = *(const f32x4*)(sh + c0), d = *(const f32x4*)(sh + c0 + 4);
        #pragma unroll
        for (int e = 0; e < 4; e++) { s8[e] = a[e]; s8[e + 4] = b[e]; h8[e] = c[e]; h8[e + 4] = d[e]; }
    }
    int a = ms[m], b = ms[m + 1];
    float acc[8] = {0,0,0,0,0,0,0,0};
    for (int r = a + half; r < b; r += 2) {
        s16x8 u = *(const s16x8*)(X + (size_t)r * H + c0);
        #pragma unroll
        for (int e = 0; e < 8; e++)
            acc[e] += fmaxf(bf2f((unsigned short)u[e]) * s8[e] + h8[e], 0.f);
    }
    float inv = (b > a) ? 1.0f / (float)(b - a) : 0.0f;
    f32x4 o0, o1;
    #pragma unroll
    for (int e = 0; e < 8; e++) {
        float tot = acc[e] + __shfl_xor(acc[e], 32);
        tot *= inv;
        if (e < 4) o0[e] = tot; else o1[e - 4] = tot;
    }
    if (half == 0) {
        *(f32x4*)(out + (size_t)m * H + c0) = o0;
        *(f32x4*)(out + (size_t)m * H + c0 + 4) = o1;
    }
}

extern "C" void kernel_launch(void* const* d_in, const int* in_sizes, int n_in,
                              void* d_out, int out_size, void* d_ws, size_t ws_size,
                              hipStream_t stream) {
    const float* f_atoms = (const float*)d_in[0];
    const float* W_in_w  = (const float*)d_in[1];
    const float* W_in_b  = (const float*)d_in[2];
    const float* w1  = (const float*)d_in[3];
    const float* b1  = (const float*)d_in[4];
    const float* g1  = (const float*)d_in[5];
    const float* be1 = (const float*)d_in[6];
    const float* w2  = (const float*)d_in[7];
    const float* b2  = (const float*)d_in[8];
    const float* g2  = (const float*)d_in[9];
    const float* be2 = (const float*)d_in[10];
    const float* epsArr = (const float*)d_in[11];
    const int* edge = (const int*)d_in[12];
    const int* seg  = (const int*)d_in[13];
    float* out = (float*)d_out;

    char* w = (char*)d_ws;
    size_t off = 0;
    auto alloc = [&](size_t bytes) {
        char* p = w + off;
        off = (off + bytes + 255) & ~(size_t)255;
        return p;
    };
    unsigned short* X   = (unsigned short*)alloc((size_t)NA * H * 2);
    unsigned short* AGG = (unsigned short*)alloc((size_t)NA * H * 2);
    unsigned short* T1  = (unsigned short*)alloc((size_t)NA * H * 2);
    unsigned short* BTall = (unsigned short*)alloc(((size_t)256 * KIN + 6 * 65536) * 2);
    float* stSum = (float*)alloc(256 * 4);
    float* stSq  = (float*)alloc(256 * 4);   // contiguous with stSum
    float* sc1 = (float*)alloc(256 * 4);
    float* sh1 = (float*)alloc(256 * 4);
    float* sc2 = (float*)alloc(256 * 4);
    float* sh2 = (float*)alloc(256 * 4);
    int* counts   = (int*)alloc((size_t)NA * 4);
    int* rowstart = (int*)alloc((size_t)(NA + 1) * 4);
    int* cursor   = (int*)alloc((size_t)NA * 4);
    int* esrc     = (int*)alloc((size_t)NE * 4);
    int* bsum     = (int*)alloc(512 * 4);
    int* ms       = (int*)alloc((NMOL + 1) * 4);

    unsigned short* BTin = BTall;
    unsigned short* BT1[3], *BT2[3];
    for (int d = 0; d < 3; ++d) {
        BT1[d] = BTall + 256 * KIN + (size_t)(2 * d) * 65536;
        BT2[d] = BTall + 256 * KIN + (size_t)(2 * d + 1) * 65536;
    }

    const int* esrcIn = edge;        // edge_index[0] = src
    const int* edst   = edge + NE;   // edge_index[1] = dst

    zero_k<<<(NA + 255) / 256, 256, 0, stream>>>(counts, stSum, rowstart);
    prep_all_k<<<(256 * KIN + 6 * 65536 + 255) / 256, 256, 0, stream>>>(W_in_w, w1, w2, BTall);

    hist_k<<<(NE + 255) / 256, 256, 0, stream>>>(edst, counts);
    scan1_k<<<391, 256, 0, stream>>>(counts, rowstart, bsum);
    scan2_k<<<1, 512, 0, stream>>>(bsum, 391);
    scan3_k<<<391, 256, 0, stream>>>(rowstart, bsum, cursor);
    fill_k<<<(NE + 255) / 256, 256, 0, stream>>>(esrcIn, edst, cursor, esrc);
    molstart_k<<<(NMOL + 256) / 256, 256, 0, stream>>>(seg, ms);

    const int GB = (NA + 127) / 128;   // 782

    // x = relu(f_atoms @ W_in + b_in)
    gemm_k<true, false, true, false, false><<<GB, 512, 0, stream>>>(
        f_atoms, BTin, W_in_b, nullptr, nullptr, X, nullptr, nullptr, NA, KIN);

    for (int d = 0; d < 3; ++d) {
        if (d == 0)
            agg_k<false><<<NA / 4, 256, 0, stream>>>(X, nullptr, nullptr,
                rowstart, esrc, epsArr, d, AGG);
        else
            agg_k<true><<<NA / 4, 256, 0, stream>>>(X, sc2, sh2,
                rowstart, esrc, epsArr, d, AGG);
        // T1 = AGG @ w1 + b1 (+stats); AGG read-once -> nt A loads
        gemm_k<false, false, false, true, true><<<GB, 512, 0, stream>>>(
            AGG, BT1[d], b1 + d * 256, nullptr, nullptr, T1, stSum, stSq, NA, 256);
        bnfin_k<<<1, 256, 0, stream>>>(stSum, stSq, g1 + d * 256, be1 + d * 256, sc1, sh1);
        // X = relu(BN(T1)) @ w2 + b2 (+stats); T1 read-once -> nt A loads
        gemm_k<false, true, false, true, true><<<GB, 512, 0, stream>>>(
            T1, BT2[d], b2 + d * 256, sc1, sh1, X, stSum, stSq, NA, 256);
        bnfin_k<<<1, 256, 0, stream>>>(stSum, stSq, g2 + d * 256, be2 + d * 256, sc2, sh2);
    }

    mean_k<<<NMOL, 64, 0, stream>>>(X, sc2, sh2, ms, out);
}

// Round 10
// 735.305 us; speedup vs baseline: 1.5795x; 1.2025x over previous
//
#include <hip/hip_runtime.h>
#include <hip/hip_bf16.h>

#define NA 100000
#define NE 800000
#define FDIM 133
#define KIN 192          // 133 padded to 3*64
#define H 256
#define NMOL 4096

typedef __attribute__((ext_vector_type(8))) short s16x8;
typedef __attribute__((ext_vector_type(4))) float f32x4;
typedef __attribute__((ext_vector_type(4))) unsigned int u32x4;

__device__ __forceinline__ float bf2f(unsigned short h) {
    unsigned u = ((unsigned)h) << 16;
    return __builtin_bit_cast(float, u);
}
__device__ __forceinline__ unsigned short f2bf(float f) {
    unsigned u = __builtin_bit_cast(unsigned, f);
    u = u + 0x7FFFu + ((u >> 16) & 1u);
    return (unsigned short)(u >> 16);
}
__device__ __forceinline__ void nt_store16(s16x8 v, void* p) {
    __builtin_nontemporal_store(__builtin_bit_cast(u32x4, v), (u32x4*)p);
}
__device__ __forceinline__ s16x8 nt_load16(const void* p) {
    return __builtin_bit_cast(s16x8, __builtin_nontemporal_load((const u32x4*)p));
}

// element offset (in shorts) of 16B group g (0..7) of row in a [*][64] bf16 tile,
// XOR-swizzled so ds_write_b128 staging and MFMA-frag ds_read_b128 are conflict-optimal
__device__ __forceinline__ int swz(int row, int g) {
    return row * 64 + ((g ^ (row & 7)) << 3);
}

// ---------------- GEMM: C[M][256] = A[M][Kpad] * BT[256][Kpad]^T (+bias) ----------------
// BM=64, BN=256, 256 threads (4 waves, wave tile 64x64). Small blocks -> 3 resident
// blocks/CU -> cross-block latency overlap (r9 lesson: GEMMs latency-bound, not BW-bound:
// dur constant 83-93us while hbm_bytes swung 150-232MB; all pipes <30%).
// Single-pass LDS-staged epilogue + nt C stores. NTA: nt A loads.
template<bool A_F32, bool AFFINE, bool RELU_OUT, bool STATS, bool NTA>
__global__ __launch_bounds__(256, 3) void gemm_k(
    const void* __restrict__ Avoid,
    const unsigned short* __restrict__ BT,
    const float* __restrict__ bias,
    const float* __restrict__ aSc, const float* __restrict__ aSh,
    unsigned short* __restrict__ C,
    float* __restrict__ stSum, float* __restrict__ stSq,
    int M, int Kpad)
{
    __shared__ short lsAB[(64 + 256) * 64];   // A[64][64] | B[256][64]; reused as C-stage [64][264]
    __shared__ float lsSc[256], lsSh[256];
    __shared__ float lsS[256], lsQ[256];
    short* lsA = lsAB;
    short* lsB = lsAB + 64 * 64;

    const int t = threadIdx.x;           // 0..255
    const int m0 = blockIdx.x * 64;

    if (STATS) { lsS[t] = 0.f; lsQ[t] = 0.f; }
    if (AFFINE) { lsSc[t] = aSc[t]; lsSh[t] = aSh[t]; }
    if (AFFINE) __syncthreads();

    const int lane = t & 63;
    const int wn = t >> 6;               // 0..3 (column quadrant)
    const int fr = lane & 15, fg = lane >> 4;
    const int srow = t >> 3;             // staging base row 0..31
    const int sg = t & 7;                // staging 16B group 0..7

    f32x4 acc[4][4];
    #pragma unroll
    for (int i = 0; i < 4; i++)
        #pragma unroll
        for (int j = 0; j < 4; j++)
            acc[i][j] = f32x4{0.f, 0.f, 0.f, 0.f};

    const int nK = Kpad >> 6;
    s16x8 ra[2], rb[8];

    auto loadRegs = [&](int kc) {
        const int k0 = kc * 64;
        #pragma unroll
        for (int p = 0; p < 2; ++p) {    // A rows srow + p*32 (0..63)
            int r = srow + p * 32;
            int ga = m0 + r;
            if (A_F32) {
                const float* Af = (const float*)Avoid;
                s16x8 v;
                #pragma unroll
                for (int e = 0; e < 8; ++e) {
                    int k = k0 + sg * 8 + e;
                    float f = (ga < M && k < FDIM) ? Af[(size_t)ga * FDIM + k] : 0.f;
                    v[e] = (short)f2bf(f);
                }
                ra[p] = v;
            } else {
                const unsigned short* A = (const unsigned short*)Avoid;
                s16x8 z = {0,0,0,0,0,0,0,0};
                const void* ap = A + (size_t)ga * Kpad + k0 + sg * 8;
                ra[p] = (ga < M) ? (NTA ? nt_load16(ap) : *(const s16x8*)ap) : z;
            }
        }
        #pragma unroll
        for (int p = 0; p < 8; ++p)      // B rows srow + p*32 (0..255)
            rb[p] = *(const s16x8*)(BT + (size_t)(srow + p * 32) * Kpad + k0 + sg * 8);
    };
    auto writeLds = [&](int kc) {
        const int k0 = kc * 64;
        #pragma unroll
        for (int p = 0; p < 2; ++p) {
            s16x8 va = ra[p];
            if (AFFINE) {
                #pragma unroll
                for (int e = 0; e < 8; ++e) {
                    int k = k0 + sg * 8 + e;
                    float f = bf2f((unsigned short)va[e]);
                    f = fmaxf(f * lsSc[k] + lsSh[k], 0.f);
                    va[e] = (short)f2bf(f);
                }
            }
            *(s16x8*)&lsA[swz(srow + p * 32, sg)] = va;
        }
        #pragma unroll
        for (int p = 0; p < 8; ++p)
            *(s16x8*)&lsB[swz(srow + p * 32, sg)] = rb[p];
    };

    loadRegs(0);
    for (int kc = 0; kc < nK; ++kc) {
        writeLds(kc);
        __syncthreads();
        if (kc + 1 < nK) loadRegs(kc + 1);   // next-chunk loads in flight across MFMAs
        #pragma unroll
        for (int ks = 0; ks < 2; ++ks) {
            s16x8 af[4], bg[4];
            #pragma unroll
            for (int mi = 0; mi < 4; ++mi)
                af[mi] = *(const s16x8*)&lsA[swz(mi * 16 + fr, ks * 4 + fg)];
            #pragma unroll
            for (int ni = 0; ni < 4; ++ni)
                bg[ni] = *(const s16x8*)&lsB[swz(wn * 64 + ni * 16 + fr, ks * 4 + fg)];
            #pragma unroll
            for (int mi = 0; mi < 4; ++mi)
                #pragma unroll
                for (int ni = 0; ni < 4; ++ni)
                    acc[mi][ni] = __builtin_amdgcn_mfma_f32_16x16x32_bf16(
                        af[mi], bg[ni], acc[mi][ni], 0, 0, 0);
        }
        __syncthreads();
    }

    // ---- single-pass LDS-staged epilogue (C/D layout: col=lane&15, row=(lane>>4)*4+reg) ----
    const int CST = 264;   // 528B row stride, 16B aligned, +4-bank shift per row
    #pragma unroll
    for (int ni = 0; ni < 4; ++ni) {
        int lcol = wn * 64 + ni * 16 + fr;
        float bc = bias[lcol];
        float cs = 0.f, cq = 0.f;
        #pragma unroll
        for (int mi = 0; mi < 4; ++mi) {
            #pragma unroll
            for (int r = 0; r < 4; ++r) {
                int rl = mi * 16 + fg * 4 + r;       // local row 0..63
                float v = acc[mi][ni][r] + bc;
                if (RELU_OUT) v = fmaxf(v, 0.f);
                if (STATS && (m0 + rl < M)) { cs += v; cq += v * v; }
                lsAB[rl * CST + lcol] = (short)f2bf(v);
            }
        }
        if (STATS) {
            atomicAdd(&lsS[lcol], cs);
            atomicAdd(&lsQ[lcol], cq);
        }
    }
    __syncthreads();
    #pragma unroll
    for (int p = 0; p < 8; ++p) {
        int idx = p * 256 + t;            // 2048 chunks of 16B
        int rl = idx >> 5;
        int col = (idx & 31) * 8;
        int row = m0 + rl;
        if (row < M)
            nt_store16(*(const s16x8*)&lsAB[rl * CST + col], C + (size_t)row * H + col);
    }
    if (STATS) {
        atomicAdd(&stSum[t], lsS[t]);
        atomicAdd(&stSq[t], lsQ[t]);
    }
}

__global__ void bnfin_k(float* __restrict__ sum, float* __restrict__ sumsq,
                        const float* __restrict__ g, const float* __restrict__ be,
                        float* __restrict__ scOut, float* __restrict__ shOut) {
    int c = threadIdx.x;
    float mean = sum[c] * (1.0f / NA);
    float var = sumsq[c] * (1.0f / NA) - mean * mean;
    float sc = g[c] * rsqrtf(var + 1e-5f);
    scOut[c] = sc;
    shOut[c] = be[c] - mean * sc;
    sum[c] = 0.f; sumsq[c] = 0.f;
}

// ---------------- init ----------------
__global__ void zero_k(int* __restrict__ counts, float* __restrict__ st, int* __restrict__ rowstart) {
    int i = blockIdx.x * 256 + threadIdx.x;
    if (i < NA) counts[i] = 0;
    if (blockIdx.x == 0) {
        st[threadIdx.x] = 0.f; st[threadIdx.x + 256] = 0.f;
        if (threadIdx.x == 0) rowstart[NA] = NE;
    }
}

// ---------------- CSR build ----------------
__global__ void hist_k(const int* __restrict__ dst, int* __restrict__ counts) {
    int e = blockIdx.x * 256 + threadIdx.x;
    if (e < NE) atomicAdd(&counts[dst[e]], 1);
}
__global__ void scan1_k(const int* __restrict__ counts, int* __restrict__ excl, int* __restrict__ bsum) {
    __shared__ int sd[256];
    int i = blockIdx.x * 256 + threadIdx.x;
    int c = (i < NA) ? counts[i] : 0;
    sd[threadIdx.x] = c;
    __syncthreads();
    for (int off = 1; off < 256; off <<= 1) {
        int v = (threadIdx.x >= off) ? sd[threadIdx.x - off] : 0;
        __syncthreads();
        sd[threadIdx.x] += v;
        __syncthreads();
    }
    if (i < NA) excl[i] = sd[threadIdx.x] - c;
    if (threadIdx.x == 255) bsum[blockIdx.x] = sd[255];
}
__global__ void scan2_k(int* __restrict__ bsum, int nb) {
    __shared__ int sd[512];
    int t = threadIdx.x;
    int v = (t < nb) ? bsum[t] : 0;
    sd[t] = v;
    __syncthreads();
    for (int off = 1; off < 512; off <<= 1) {
        int u = (t >= off) ? sd[t - off] : 0;
        __syncthreads();
        sd[t] += u;
        __syncthreads();
    }
    if (t < nb) bsum[t] = sd[t] - v;
}
__global__ void scan3_k(int* __restrict__ rowstart, const int* __restrict__ bsum, int* __restrict__ cursor) {
    int i = blockIdx.x * 256 + threadIdx.x;
    if (i < NA) {
        int v = rowstart[i] + bsum[blockIdx.x];
        rowstart[i] = v;
        cursor[i] = v;
    }
}
__global__ void fill_k(const int* __restrict__ src, const int* __restrict__ dstArr,
                       int* __restrict__ cursor, int* __restrict__ esrc) {
    int e = blockIdx.x * 256 + threadIdx.x;
    if (e < NE) {
        int d = dstArr[e];
        int pos = atomicAdd(&cursor[d], 1);
        esrc[pos] = src[e];
    }
}

// ---------------- neighbor aggregation (round-5 proven structure) ----------------
template<bool AFF>
__global__ __launch_bounds__(256) void agg_k(const unsigned short* __restrict__ X,
    const float* __restrict__ sc, const float* __restrict__ sh,
    const int* __restrict__ rowstart,
    const int* __restrict__ esrc, const float* __restrict__ epsArr, int layer,
    unsigned short* __restrict__ AGG)
{
    int wid = threadIdx.x >> 6, lane = threadIdx.x & 63;
    int row = blockIdx.x * 4 + wid;
    int half = lane >> 5;
    int c0 = (lane & 31) * 8;

    float s8[8], h8[8];
    if (AFF) {
        f32x4 a = *(const f32x4*)(sc + c0), b = *(const f32x4*)(sc + c0 + 4);
        f32x4 c = *(const f32x4*)(sh + c0), d = *(const f32x4*)(sh + c0 + 4);
        #pragma unroll
        for (int e = 0; e < 4; e++) { s8[e] = a[e]; s8[e + 4] = b[e]; h8[e] = c[e]; h8[e + 4] = d[e]; }
    }

    float a0[8] = {0,0,0,0,0,0,0,0}, a1[8] = {0,0,0,0,0,0,0,0};
    auto addv = [&](s16x8 u, float* a) {
        #pragma unroll
        for (int e = 0; e < 8; e++) {
            float f = bf2f((unsigned short)u[e]);
            if (AFF) f = fmaxf(f * s8[e] + h8[e], 0.f);
            a[e] += f;
        }
    };

    int s = rowstart[row], eEnd = rowstart[row + 1];
    int cnt = eEnd - s, mid = s + (cnt >> 1);
    int i = half ? mid : s;
    int end = half ? eEnd : mid;
    for (; i + 3 < end; i += 4) {
        int e0 = esrc[i], e1 = esrc[i + 1], e2 = esrc[i + 2], e3 = esrc[i + 3];
        s16x8 u0 = *(const s16x8*)(X + (size_t)e0 * H + c0);
        s16x8 u1 = *(const s16x8*)(X + (size_t)e1 * H + c0);
        s16x8 u2 = *(const s16x8*)(X + (size_t)e2 * H + c0);
        s16x8 u3 = *(const s16x8*)(X + (size_t)e3 * H + c0);
        addv(u0, a0); addv(u1, a1); addv(u2, a0); addv(u3, a1);
    }
    for (; i < end; ++i) {
        int e0 = esrc[i];
        s16x8 u = *(const s16x8*)(X + (size_t)e0 * H + c0);
        addv(u, a0);
    }

    if (half == 0) {   // self term
        float e1 = 1.0f + epsArr[layer];
        s16x8 u = *(const s16x8*)(X + (size_t)row * H + c0);
        #pragma unroll
        for (int e = 0; e < 8; e++) {
            float f = bf2f((unsigned short)u[e]);
            if (AFF) f = fmaxf(f * s8[e] + h8[e], 0.f);
            a0[e] += f * e1;
        }
    }

    s16x8 o;
    #pragma unroll
    for (int e = 0; e < 8; e++) {
        float tot = a0[e] + a1[e];
        tot += __shfl_xor(tot, 32);
        o[e] = (short)f2bf(tot);
    }
    if (half == 0)
        nt_store16(o, AGG + (size_t)row * H + c0);
}

// ---------------- weight prep ----------------
__global__ void prep_all_k(const float* __restrict__ Win, const float* __restrict__ w1,
                           const float* __restrict__ w2, unsigned short* __restrict__ BTall) {
    int i = blockIdx.x * 256 + threadIdx.x;
    const int NIN = 256 * KIN;
    if (i < NIN) {
        int n = i / KIN, k = i % KIN;
        BTall[i] = (k < FDIM) ? f2bf(Win[(size_t)k * 256 + n]) : (unsigned short)0;
    } else if (i < NIN + 6 * 65536) {
        int j = i - NIN;
        int d = j >> 16, r = j & 65535;
        int n = r >> 8, k = r & 255;
        const float* W = (d & 1) ? w2 : w1;
        BTall[i] = f2bf(W[(size_t)(d >> 1) * 65536 + (size_t)k * 256 + n]);
    }
}

// ---------------- segment mean ----------------
__global__ void molstart_k(const int* __restrict__ seg, int* __restrict__ ms) {
    int m = blockIdx.x * 256 + threadIdx.x;
    if (m <= NMOL) {
        int lo = 0, hi = NA;
        while (lo < hi) { int mid = (lo + hi) >> 1; if (seg[mid] < m) lo = mid + 1; else hi = mid; }
        ms[m] = lo;
    }
}
__global__ __launch_bounds__(64) void mean_k(const unsigned short* __restrict__ X,
    const float* __restrict__ sc, const float* __restrict__ sh,
    const int* __restrict__ ms, float* __restrict__ out)
{
    int m = blockIdx.x, lane = threadIdx.x;
    int half = lane >> 5;
    int c0 = (lane & 31) * 8;
    float s8[8], h8[8];
    {
        f32x4 a = *(const f32x4*)(sc + c0), b = *(const f32x4*)(sc + c0 + 4);
        f32x4 c = *(const f32x4*)(sh + c0), d = *(const f32x4*)(sh + c0 + 4);
        #pragma unroll
        for (int e = 0; e < 4; e++) { s8[e] = a[e]; s8[e + 4] = b[e]; h8[e] = c[e]; h8[e + 4] = d[e]; }
    }
    int a = ms[m], b = ms[m + 1];
    float acc[8] = {0,0,0,0,0,0,0,0};
    for (int r = a + half; r < b; r += 2) {
        s16x8 u = *(const s16x8*)(X + (size_t)r * H + c0);
        #pragma unroll
        for (int e = 0; e < 8; e++)
            acc[e] += fmaxf(bf2f((unsigned short)u[e]) * s8[e] + h8[e], 0.f);
    }
    float inv = (b > a) ? 1.0f / (float)(b - a) : 0.0f;
    f32x4 o0, o1;
    #pragma unroll
    for (int e = 0; e < 8; e++) {
        float tot = acc[e] + __shfl_xor(acc[e], 32);
        tot *= inv;
        if (e < 4) o0[e] = tot; else o1[e - 4] = tot;
    }
    if (half == 0) {
        *(f32x4*)(out + (size_t)m * H + c0) = o0;
        *(f32x4*)(out + (size_t)m * H + c0 + 4) = o1;
    }
}

extern "C" void kernel_launch(void* const* d_in, const int* in_sizes, int n_in,
                              void* d_out, int out_size, void* d_ws, size_t ws_size,
                              hipStream_t stream) {
    const float* f_atoms = (const float*)d_in[0];
    const float* W_in_w  = (const float*)d_in[1];
    const float* W_in_b  = (const float*)d_in[2];
    const float* w1  = (const float*)d_in[3];
    const float* b1  = (const float*)d_in[4];
    const float* g1  = (const float*)d_in[5];
    const float* be1 = (const float*)d_in[6];
    const float* w2  = (const float*)d_in[7];
    const float* b2  = (const float*)d_in[8];
    const float* g2  = (const float*)d_in[9];
    const float* be2 = (const float*)d_in[10];
    const float* epsArr = (const float*)d_in[11];
    const int* edge = (const int*)d_in[12];
    const int* seg  = (const int*)d_in[13];
    float* out = (float*)d_out;

    char* w = (char*)d_ws;
    size_t off = 0;
    auto alloc = [&](size_t bytes) {
        char* p = w + off;
        off = (off + bytes + 255) & ~(size_t)255;
        return p;
    };
    unsigned short* X   = (unsigned short*)alloc((size_t)NA * H * 2);
    unsigned short* AGG = (unsigned short*)alloc((size_t)NA * H * 2);
    unsigned short* T1  = (unsigned short*)alloc((size_t)NA * H * 2);
    unsigned short* BTall = (unsigned short*)alloc(((size_t)256 * KIN + 6 * 65536) * 2);
    float* stSum = (float*)alloc(256 * 4);
    float* stSq  = (float*)alloc(256 * 4);   // contiguous with stSum
    float* sc1 = (float*)alloc(256 * 4);
    float* sh1 = (float*)alloc(256 * 4);
    float* sc2 = (float*)alloc(256 * 4);
    float* sh2 = (float*)alloc(256 * 4);
    int* counts   = (int*)alloc((size_t)NA * 4);
    int* rowstart = (int*)alloc((size_t)(NA + 1) * 4);
    int* cursor   = (int*)alloc((size_t)NA * 4);
    int* esrc     = (int*)alloc((size_t)NE * 4);
    int* bsum     = (int*)alloc(512 * 4);
    int* ms       = (int*)alloc((NMOL + 1) * 4);

    unsigned short* BTin = BTall;
    unsigned short* BT1[3], *BT2[3];
    for (int d = 0; d < 3; ++d) {
        BT1[d] = BTall + 256 * KIN + (size_t)(2 * d) * 65536;
        BT2[d] = BTall + 256 * KIN + (size_t)(2 * d + 1) * 65536;
    }

    const int* esrcIn = edge;        // edge_index[0] = src
    const int* edst   = edge + NE;   // edge_index[1] = dst

    zero_k<<<(NA + 255) / 256, 256, 0, stream>>>(counts, stSum, rowstart);
    prep_all_k<<<(256 * KIN + 6 * 65536 + 255) / 256, 256, 0, stream>>>(W_in_w, w1, w2, BTall);

    hist_k<<<(NE + 255) / 256, 256, 0, stream>>>(edst, counts);
    scan1_k<<<391, 256, 0, stream>>>(counts, rowstart, bsum);
    scan2_k<<<1, 512, 0, stream>>>(bsum, 391);
    scan3_k<<<391, 256, 0, stream>>>(rowstart, bsum, cursor);
    fill_k<<<(NE + 255) / 256, 256, 0, stream>>>(esrcIn, edst, cursor, esrc);
    molstart_k<<<(NMOL + 256) / 256, 256, 0, stream>>>(seg, ms);

    const int GB = (NA + 63) / 64;   // 1563

    // x = relu(f_atoms @ W_in + b_in)
    gemm_k<true, false, true, false, false><<<GB, 256, 0, stream>>>(
        f_atoms, BTin, W_in_b, nullptr, nullptr, X, nullptr, nullptr, NA, KIN);

    for (int d = 0; d < 3; ++d) {
        if (d == 0)
            agg_k<false><<<NA / 4, 256, 0, stream>>>(X, nullptr, nullptr,
                rowstart, esrc, epsArr, d, AGG);
        else
            agg_k<true><<<NA / 4, 256, 0, stream>>>(X, sc2, sh2,
                rowstart, esrc, epsArr, d, AGG);
        // T1 = AGG @ w1 + b1 (+stats); AGG read-once -> nt A loads
        gemm_k<false, false, false, true, true><<<GB, 256, 0, stream>>>(
            AGG, BT1[d], b1 + d * 256, nullptr, nullptr, T1, stSum, stSq, NA, 256);
        bnfin_k<<<1, 256, 0, stream>>>(stSum, stSq, g1 + d * 256, be1 + d * 256, sc1, sh1);
        // X = relu(BN(T1)) @ w2 + b2 (+stats); T1 read-once -> nt A loads
        gemm_k<false, true, false, true, true><<<GB, 256, 0, stream>>>(
            T1, BT2[d], b2 + d * 256, sc1, sh1, X, stSum, stSq, NA, 256);
        bnfin_k<<<1, 256, 0, stream>>>(stSum, stSq, g2 + d * 256, be2 + d * 256, sc2, sh2);
    }

    mean_k<<<NMOL, 64, 0, stream>>>(X, sc2, sh2, ms, out);
}